// Round 5
// baseline (360.766 us; speedup 1.0000x reference)
//
#include <hip/hip_runtime.h>

#define N_ 16
#define T_ 8
#define L_ 197
#define H_ 12
#define D_ 64
#define Q_ 196
#define C_ 768
#define KP 224          // padded K/pos dimension (7 x 32)
#define ENT 1792        // 8 dchunks * 224 pos, 16B entries per (nt,h) plane
#define ATS 216         // attn epilogue LDS row stride (ushorts)
#define APLANE 2112     // mix: As plane stride bytes (2048 + 64 skew)

typedef unsigned short ushort_t;
typedef __bf16 bf16x8 __attribute__((ext_vector_type(8)));
typedef float floatx4 __attribute__((ext_vector_type(4)));

// async global->LDS, 16B per lane, dst = uniform base + lane*16
#define GLD_LDS16(g, l)                                                    \
  __builtin_amdgcn_global_load_lds(                                        \
      (const __attribute__((address_space(1))) void*)(g),                  \
      (__attribute__((address_space(3))) void*)(l), 16, 0, 0)

static __device__ inline ushort_t f2bf(float x) {
  unsigned int u = __float_as_uint(x);
  u += 0x7fffu + ((u >> 16) & 1u);       // RNE
  return (ushort_t)(u >> 16);
}
static __device__ inline unsigned int pack2(float a, float b) {
  return (unsigned int)f2bf(a) | ((unsigned int)f2bf(b) << 16);
}

// ------------- Pass 0: q,k fp32 -> bf16 planes [nt][h][dc 8][pos 224] ------
// One block per (nt, h, q|k) plane. ALL 14 float4 loads are front-loaded
// into named registers (sched_barrier-pinned) so ~14 HBM ops stay in flight
// per wave. launch_bounds(256,4) raises the VGPR cap to 128 to hold the
// payload. Then pack via XOR-swizzled LDS (conflict-free both phases) and
// stream the 28KB output plane contiguously. Pad pos 196..223 = 0.
__global__ __launch_bounds__(256, 4) void convert_kernel(
    const float* __restrict__ q, const float* __restrict__ k,
    uint4* __restrict__ qb, uint4* __restrict__ kb) {
  const int nt  = blockIdx.x;      // 0..127
  const int h   = blockIdx.y;      // 0..11
  const int inp = blockIdx.z;      // 0 = q, 1 = k
  const int tid = threadIdx.x;

  const float* src = inp ? k : q;
  const float sc = inp ? 1.f : 0.125f;
  uint4* dst = (inp ? kb : qb) + ((size_t)nt * H_ + h) * ENT;

  __shared__ __align__(16) uint4 lds[8 * KP];   // 28 KB: [dc][pos swizzled]

  const float* base = src + ((size_t)nt * L_ + 1) * (H_ * D_) + h * D_;

  // phase 1a: issue all loads (r<6 unconditional; r=6 valid iff tid<32,
  // since 1536+tid < 1568). Static indexing -> registers, no scratch.
  float4 va[7], vb[7];
  #pragma unroll
  for (int r = 0; r < 7; r++) {
    int e = tid + 256 * r;               // < 1792; valid < 1568
    int pos = e >> 3, dc = e & 7;
    if (r < 6 || tid < 32) {
      const float* p = base + (size_t)pos * (H_ * D_) + dc * 8;
      va[r] = *(const float4*)p;
      vb[r] = *(const float4*)(p + 4);
    }
  }
  __builtin_amdgcn_sched_barrier(0);     // keep the 14-load cluster ahead

  // phase 1b: pack + swizzled LDS write (waits retire oldest-first)
  #pragma unroll
  for (int r = 0; r < 7; r++) {
    int e = tid + 256 * r;
    int pos = e >> 3, dc = e & 7;
    if (r < 6 || tid < 32) {
      uint4 o;
      o.x = pack2(va[r].x * sc, va[r].y * sc);
      o.y = pack2(va[r].z * sc, va[r].w * sc);
      o.z = pack2(vb[r].x * sc, vb[r].y * sc);
      o.w = pack2(vb[r].z * sc, vb[r].w * sc);
      lds[dc * KP + ((pos & ~7) | ((pos ^ dc) & 7))] = o;
    }
  }
  __syncthreads();

  // phase 2: contiguous plane store (1 KB per wave per iter); pad pos = 0
  #pragma unroll
  for (int r = 0; r < 7; r++) {
    int e = tid + 256 * r;               // output entry, 0..1791
    int dc = e / KP, pos = e - dc * KP;
    uint4 v;
    if (pos < 196) v = lds[dc * KP + ((pos & ~7) | ((pos ^ dc) & 7))];
    else           v = (uint4){0u, 0u, 0u, 0u};
    dst[e] = v;
  }
}

// ------------- Stage 1: A[qi][nt][k] = mean_h softmax_k(QK^T/8), bf16 ------
// 1D grid 896, XCD-swizzled. K double-buffered in LDS via global_load_lds;
// raw s_barrier + counted vmcnt(9) keeps the next head's DMA (7 loads) and
// Q-frag loads (2) in flight across barriers (T3+T4). Q ping-pongs between
// two named register sets (static indexing only).
__global__ __launch_bounds__(256, 2) void attn_kernel(
    const uint4* __restrict__ qb, const uint4* __restrict__ kb,
    ushort_t* __restrict__ A1, ushort_t* __restrict__ A2) {
  const int lin  = blockIdx.x;          // 0..895
  const int xcd  = lin & 7;
  const int slot = lin >> 3;            // 0..111
  const int g    = (slot >> 2) * 8 + xcd;   // K-group 0..223
  const int b    = slot & 3;            // q-row block of 64
  const int half = g / 112;
  const int nt   = g - half * 112;
  const int n  = nt / 7, tp = nt % 7;
  const int tq = (half == 0) ? tp + 1 : tp;
  const int tk = (half == 0) ? tp     : tp + 1;
  const int ntq = n * T_ + tq;
  const int ntk = n * T_ + tk;

  const uint4* qpl = qb + (size_t)ntq * H_ * ENT;
  const uint4* kpl = kb + (size_t)ntk * H_ * ENT;
  ushort_t* Ah = (half == 0) ? A1 : A2;

  __shared__ __align__(16) uint4 ks[2][ENT];   // 2 x 28 KB double buffer
  ushort_t* at = (ushort_t*)ks;                // epilogue alias (27.6 KB, in ks[0])

  const int tid  = threadIdx.x;
  const int lane = tid & 63;
  const int wv   = tid >> 6;
  const int quad = lane >> 4;
  const int l15  = lane & 15;
  const int qi_b = 64 * b + 16 * wv;

  float accA[13][4];
  #pragma unroll
  for (int t = 0; t < 13; t++)
    #pragma unroll
    for (int r = 0; r < 4; r++) accA[t][r] = 0.f;

  // per-wave K DMA for head h into buffer bufp (7 vmem ops / wave)
  auto stage = [&](int h, uint4* bufp) {
    #pragma unroll
    for (int r = 0; r < 7; r++)
      GLD_LDS16(kpl + (size_t)h * ENT + 256 * r + 64 * wv + lane,
                (char*)bufp + (256 * r + 64 * wv) * 16);
  };
  // Q fragments for head h (2 vmem ops / lane)
  auto loadq = [&](int h, bf16x8* qf) {
    #pragma unroll
    for (int kk = 0; kk < 2; kk++)
      qf[kk] = *(const bf16x8*)&qpl[(size_t)h * ENT + (quad + 4 * kk) * KP + qi_b + l15];
  };

  // one head: wait(own DMA(h)+Q(h) landed, keep next head's 9 in flight) ->
  // barrier -> MFMA from bufp -> barrier -> issue head h+2 into same buffer
  // (parity) -> softmax (overlaps the in-flight DMA).
  auto headbody = [&](int h, uint4* bufp, bf16x8* qf, bool lastwait) {
    if (lastwait) asm volatile("s_waitcnt vmcnt(0)" ::: "memory");
    else          asm volatile("s_waitcnt vmcnt(9)" ::: "memory");
    __builtin_amdgcn_s_barrier();
    asm volatile("" ::: "memory");       // no LDS read hoists above barrier

    const ushort_t* bu = (const ushort_t*)bufp;
    floatx4 S[13];
    #pragma unroll
    for (int t = 0; t < 13; t++) S[t] = (floatx4){0.f, 0.f, 0.f, 0.f};
    #pragma unroll
    for (int kk = 0; kk < 2; kk++)
      #pragma unroll
      for (int t = 0; t < 13; t++) {
        bf16x8 bbv = *(const bf16x8*)&bu[((quad + 4 * kk) * KP + 16 * t + l15) * 8];
        S[t] = __builtin_amdgcn_mfma_f32_16x16x32_bf16(qf[kk], bbv, S[t], 0, 0, 0);
      }

    asm volatile("" ::: "memory");       // no LDS read sinks below barrier
    __builtin_amdgcn_s_barrier();        // all waves done reading bufp
    if (h + 2 < H_) {                    // prefetch 2 heads ahead
      loadq(h + 2, qf);
      stage(h + 2, bufp);
      // keep the 9-op issue cluster together; nothing drifts across softmax
      __builtin_amdgcn_sched_barrier(0);
    }

    // softmax over k (196 valid), accumulate P/rowsum (pure VALU, overlaps DMA)
    #pragma unroll
    for (int r = 0; r < 4; r++) {
      float s = 0.f;
      #pragma unroll
      for (int t = 0; t < 13; t++) {
        float e_ = (t == 12 && l15 >= 4) ? 0.f : __expf(S[t][r]);
        S[t][r] = e_;
        s += e_;
      }
      #pragma unroll
      for (int off = 1; off < 16; off <<= 1) s += __shfl_xor(s, off);
      float inv = 1.f / s;
      #pragma unroll
      for (int t = 0; t < 13; t++) accA[t][r] += S[t][r] * inv;
    }
  };

  // prologue: heads 0 and 1 in flight. Issue-order MUST be {Q0,D0} then
  // {Q1,D1} for the vmcnt(9) count to drain exactly head 0 at the first
  // wait — sched_barrier(0) pins the groups (plain Q loads could otherwise
  // hoist above the LDS-DMA builtins).
  bf16x8 qfA[2], qfB[2];
  loadq(0, qfA); stage(0, ks[0]);
  __builtin_amdgcn_sched_barrier(0);
  loadq(1, qfB); stage(1, ks[1]);
  __builtin_amdgcn_sched_barrier(0);

  #pragma unroll 1
  for (int hh = 0; hh < 6; hh++) {
    headbody(2 * hh,     ks[0], qfA, false);
    headbody(2 * hh + 1, ks[1], qfB, hh == 5);
  }

  // epilogue: transpose accA via LDS (wave-private rows), uint4 stores
  const float s12 = 1.f / 12.f;
  #pragma unroll
  for (int t = 0; t < 13; t++)
    #pragma unroll
    for (int r = 0; r < 4; r++)
      at[(16 * wv + 4 * quad + r) * ATS + 16 * t + l15] = f2bf(accA[t][r] * s12);
  #pragma unroll
  for (int i = 0; i < 7; i++) {
    int e = lane + 64 * i;             // 16 rows x 26 uint4 = 416
    if (e < 416) {
      int row = e / 26, col = e - row * 26;
      uint4 v = *(const uint4*)&at[(16 * wv + row) * ATS + col * 8];
      int qi = qi_b + row;
      if (qi < Q_)
        *(uint4*)(Ah + ((size_t)qi * (N_ * T_) + ntq) * KP + col * 8) = v;
    }
  }
}

// ------------- Stage 2: out[nt,qi,c] = sum_half A_h[qi] @ gather(W_h) ------
// grid (6 c-tiles of 128, 196 qi), block 256. T3+T4 pipeline (mirrors attn):
// raw s_barrier + counted vmcnt(6); parity As double-buffer; prefetch
// distance 2 so each chunk's {2 DMA + 4 W-gather} group has a FULL chunk
// body to land. Ws rows are wave-private (write+read by owner wave only),
// so the W-commit overlaps other waves' barrier wait. Fully unrolled:
// idxr[] stays statically indexed, pwA/pwB are named register sets.
__global__ __launch_bounds__(256, 4) void mix_kernel(
    const ushort_t* __restrict__ A1, const ushort_t* __restrict__ A2,
    const float* __restrict__ w1, const float* __restrict__ w2,
    const int* __restrict__ idx, float* __restrict__ out) {
  const int ct = blockIdx.x;   // 0..5
  const int qi = blockIdx.y;   // 0..195
  const int tid  = threadIdx.x;
  const int lane = tid & 63;
  const int wv   = tid >> 6;
  const int quad = lane >> 4;
  const int l15  = lane & 15;
  const int p    = lane >> 2;  // k-pair 0..15
  const int cq   = lane & 3;   // c-chunk slot

  __shared__ __align__(16) char As[2][4 * APLANE];   // 2 x 8448 B
  __shared__ ushort_t Ws[128][40];                   // wave-private rows

  // idx regs: this lane's two k-rows per chunk (clamped; A=0 kills pad cols)
  int idxr0[7], idxr1[7];
  #pragma unroll
  for (int kc = 0; kc < 7; kc++) {
    int off = 32 * kc + 2 * p;
    if (off > 194) off = 194;
    int2 pr = *(const int2*)(idx + (size_t)qi * Q_ + off);
    idxr0[kc] = pr.x; idxr1[kc] = pr.y;
  }

  floatx4 acc[8][2];
  #pragma unroll
  for (int mt = 0; mt < 8; mt++)
    #pragma unroll
    for (int u = 0; u < 2; u++) acc[mt][u] = (floatx4){0.f, 0.f, 0.f, 0.f};

  const int cbase = ct * 128 + wv * 32;

  // W-gather for chunk ch into a pw reg set (4 vmem ops / lane)
  auto gather = [&](int ch, float4 (&pw)[2][2]) {
    const float* w_ = (ch >= 7) ? w2 : w1;
    const int nk = ch % 7;               // ch is a literal -> static idxr index
    const int r0 = idxr0[nk], r1 = idxr1[nk];
    #pragma unroll
    for (int u = 0; u < 2; u++) {
      pw[0][u] = *(const float4*)(w_ + (size_t)r0 * C_ + cbase + (cq + 4 * u) * 4);
      pw[1][u] = *(const float4*)(w_ + (size_t)r1 * C_ + cbase + (cq + 4 * u) * 4);
    }
  };
  // A-tile DMA for chunk ch into buffer buf (2 vmem ops / wave)
  auto dma = [&](int ch, char* buf) {
    const ushort_t* Ah_ = (ch >= 7) ? A2 : A1;
    const int nk = ch % 7;
    #pragma unroll
    for (int r = 0; r < 2; r++)
      GLD_LDS16(Ah_ + ((size_t)qi * 128 + r * 64 + lane) * KP + 32 * nk + wv * 8,
                buf + wv * APLANE + r * 1024);
  };

  // prologue: chunks 0 and 1 in flight (group order pinned for vmcnt count:
  // G0 = {4 gather + 2 DMA}, then G1 = same -> 12 outstanding)
  float4 pwA[2][2], pwB[2][2];
  gather(0, pwA); dma(0, As[0]);
  __builtin_amdgcn_sched_barrier(0);
  gather(1, pwB); dma(1, As[1]);
  __builtin_amdgcn_sched_barrier(0);

  // one chunk: wait(own group landed, keep next chunk's 6 in flight) ->
  // commit W (wave-private, overlaps barrier) -> barrier -> MFMA ->
  // barrier -> issue chunk ht+2 into the same As buffer (parity).
  auto body = [&](int ht, char* bufp, float4 (&pwX)[2][2], bool lastwait) {
    if (lastwait) asm volatile("s_waitcnt vmcnt(0)" ::: "memory");
    else          asm volatile("s_waitcnt vmcnt(6)" ::: "memory");

    // commit this chunk's W (rows wv*32.. are read only by this wave)
    #pragma unroll
    for (int u = 0; u < 2; u++) {
      const float* f0 = (const float*)&pwX[0][u];
      const float* f1 = (const float*)&pwX[1][u];
      #pragma unroll
      for (int e = 0; e < 4; e++)
        *(unsigned int*)&Ws[wv * 32 + (cq + 4 * u) * 4 + e][2 * p] = pack2(f0[e], f1[e]);
    }

    __builtin_amdgcn_s_barrier();        // As[parity] DMA visible block-wide
    asm volatile("" ::: "memory");       // no LDS read hoists above barrier

    bf16x8 bfv[2];
    #pragma unroll
    for (int u = 0; u < 2; u++)
      bfv[u] = *(const bf16x8*)&Ws[wv * 32 + 16 * u + l15][8 * quad];
    #pragma unroll
    for (int mt = 0; mt < 8; mt++) {
      bf16x8 a = *(const bf16x8*)(bufp + quad * APLANE + (16 * mt + l15) * 16);
      acc[mt][0] = __builtin_amdgcn_mfma_f32_16x16x32_bf16(a, bfv[0], acc[mt][0], 0, 0, 0);
      acc[mt][1] = __builtin_amdgcn_mfma_f32_16x16x32_bf16(a, bfv[1], acc[mt][1], 0, 0, 0);
    }

    asm volatile("" ::: "memory");       // no LDS read sinks below barrier
    __builtin_amdgcn_s_barrier();        // all waves done reading bufp
    if (ht + 2 < 14) {                   // prefetch 2 chunks ahead
      gather(ht + 2, pwX);
      dma(ht + 2, bufp);
      __builtin_amdgcn_sched_barrier(0); // keep the 6-op group together
    }
  };

  #pragma unroll
  for (int ht = 0; ht < 14; ht++) {
    if (ht & 1) body(ht, As[1], pwB, ht == 13);
    else        body(ht, As[0], pwA, false);
  }

  #pragma unroll
  for (int u = 0; u < 2; u++) {
    const int c = ct * 128 + 32 * wv + 16 * u + l15;
    #pragma unroll
    for (int mt = 0; mt < 8; mt++)
      #pragma unroll
      for (int r = 0; r < 4; r++) {
        int m = 16 * mt + 4 * quad + r;
        out[((size_t)m * L_ + 1 + qi) * C_ + c] = acc[mt][u][r];
      }
  }
  if (qi == 0) {
    #pragma unroll
    for (int u = 0; u < 2; u++) {
      const int c = ct * 128 + 32 * wv + 16 * u + l15;
      #pragma unroll
      for (int mt = 0; mt < 8; mt++)
        #pragma unroll
        for (int r = 0; r < 4; r++) {
          int m = 16 * mt + 4 * quad + r;
          out[(size_t)m * L_ * C_ + c] = 0.f;
        }
    }
  }
}

extern "C" void kernel_launch(void* const* d_in, const int* in_sizes, int n_in,
                              void* d_out, int out_size, void* d_ws, size_t ws_size,
                              hipStream_t stream) {
  const float* q  = (const float*)d_in[0];
  const float* k  = (const float*)d_in[1];
  const float* w1 = (const float*)d_in[2];
  const float* w2 = (const float*)d_in[3];
  const int* idx  = (const int*)d_in[4];
  float* out = (float*)d_out;

  const size_t plane_tot = (size_t)(N_ * T_) * H_ * ENT;   // uint4 entries
  uint4* qb = (uint4*)d_ws;
  uint4* kb = qb + plane_tot;
  ushort_t* A1 = (ushort_t*)(kb + plane_tot);
  size_t Aelems = (size_t)Q_ * (N_ * T_) * KP;
  ushort_t* A2 = A1 + Aelems;

  // zero A buffers: covers k-pad cols and the empty t-slots
  hipMemsetAsync(A1, 0, Aelems * 2 * sizeof(ushort_t), stream);

  convert_kernel<<<dim3(N_ * T_, H_, 2), 256, 0, stream>>>(q, k, qb, kb);
  attn_kernel<<<dim3(896), 256, 0, stream>>>(qb, kb, A1, A2);
  mix_kernel<<<dim3(6, Q_), 256, 0, stream>>>(A1, A2, w1, w2, idx, out);
}

// Round 7
// 328.040 us; speedup vs baseline: 1.0998x; 1.0998x over previous
//
#include <hip/hip_runtime.h>

#define N_ 16
#define T_ 8
#define L_ 197
#define H_ 12
#define D_ 64
#define Q_ 196
#define C_ 768
#define KP 224          // padded K/pos dimension (7 x 32)
#define ENT 1792        // 8 dchunks * 224 pos, 16B entries per (nt,h) plane
#define ATS 216         // attn epilogue LDS row stride (ushorts)
#define APLANE 2112     // mix: As plane stride bytes (2048 + 64 skew)

typedef unsigned short ushort_t;
typedef __bf16 bf16x8 __attribute__((ext_vector_type(8)));
typedef float floatx4 __attribute__((ext_vector_type(4)));

// async global->LDS, 16B per lane, dst = uniform base + lane*16
#define GLD_LDS16(g, l)                                                    \
  __builtin_amdgcn_global_load_lds(                                        \
      (const __attribute__((address_space(1))) void*)(g),                  \
      (__attribute__((address_space(3))) void*)(l), 16, 0, 0)

static __device__ inline ushort_t f2bf(float x) {
  unsigned int u = __float_as_uint(x);
  u += 0x7fffu + ((u >> 16) & 1u);       // RNE
  return (ushort_t)(u >> 16);
}
static __device__ inline unsigned int pack2(float a, float b) {
  return (unsigned int)f2bf(a) | ((unsigned int)f2bf(b) << 16);
}

// ------------- Pass 0: k fp32 -> bf16 planes [nt][h][dc 8][pos 224] -------
// K only — Q is consumed fp32-direct by attn (per-lane register loads need
// no layout transform). One block per (nt, h) plane. ALL 14 float4 loads
// front-loaded into named registers (sched_barrier-pinned) for MLP; pack
// via XOR-swizzled LDS (conflict-free both phases); stream the 28KB output
// plane contiguously. Pad pos 196..223 = 0.
__global__ __launch_bounds__(256, 4) void convert_kernel(
    const float* __restrict__ k, uint4* __restrict__ kb) {
  const int nt  = blockIdx.x;      // 0..127
  const int h   = blockIdx.y;      // 0..11
  const int tid = threadIdx.x;

  uint4* dst = kb + ((size_t)nt * H_ + h) * ENT;

  __shared__ __align__(16) uint4 lds[8 * KP];   // 28 KB: [dc][pos swizzled]

  const float* base = k + ((size_t)nt * L_ + 1) * (H_ * D_) + h * D_;

  // phase 1a: issue all loads (r<6 unconditional; r=6 valid iff tid<32,
  // since 1536+tid < 1568). Static indexing -> registers, no scratch.
  float4 va[7], vb[7];
  #pragma unroll
  for (int r = 0; r < 7; r++) {
    int e = tid + 256 * r;               // < 1792; valid < 1568
    int pos = e >> 3, dc = e & 7;
    if (r < 6 || tid < 32) {
      const float* p = base + (size_t)pos * (H_ * D_) + dc * 8;
      va[r] = *(const float4*)p;
      vb[r] = *(const float4*)(p + 4);
    }
  }
  __builtin_amdgcn_sched_barrier(0);     // keep the 14-load cluster ahead

  // phase 1b: pack + swizzled LDS write (waits retire oldest-first)
  #pragma unroll
  for (int r = 0; r < 7; r++) {
    int e = tid + 256 * r;
    int pos = e >> 3, dc = e & 7;
    if (r < 6 || tid < 32) {
      uint4 o;
      o.x = pack2(va[r].x, va[r].y);
      o.y = pack2(va[r].z, va[r].w);
      o.z = pack2(vb[r].x, vb[r].y);
      o.w = pack2(vb[r].z, vb[r].w);
      lds[dc * KP + ((pos & ~7) | ((pos ^ dc) & 7))] = o;
    }
  }
  __syncthreads();

  // phase 2: contiguous plane store (1 KB per wave per iter); pad pos = 0
  #pragma unroll
  for (int r = 0; r < 7; r++) {
    int e = tid + 256 * r;               // output entry, 0..1791
    int dc = e / KP, pos = e - dc * KP;
    uint4 v;
    if (pos < 196) v = lds[dc * KP + ((pos & ~7) | ((pos ^ dc) & 7))];
    else           v = (uint4){0u, 0u, 0u, 0u};
    dst[e] = v;
  }
}

// ------------- Stage 1: A[qi][nt][k] = mean_h softmax_k(QK^T/8), bf16 ------
// 1D grid 896, XCD-swizzled. K double-buffered in LDS via global_load_lds;
// raw s_barrier + counted vmcnt(11) keeps the next head's group (7 DMA +
// 4 fp32 Q-loads) in flight across barriers (T3+T4). Q is read fp32-direct
// from the input tensor (row CLAMPED to 195 — rows >=196 are masked at the
// epilogue; unclamped reads ran past the allocation on the last plane and
// crashed round 6) and converted in-register (same pack2 RNE path).
__global__ __launch_bounds__(256, 2) void attn_kernel(
    const float* __restrict__ q, const uint4* __restrict__ kb,
    ushort_t* __restrict__ A1, ushort_t* __restrict__ A2) {
  const int lin  = blockIdx.x;          // 0..895
  const int xcd  = lin & 7;
  const int slot = lin >> 3;            // 0..111
  const int g    = (slot >> 2) * 8 + xcd;   // K-group 0..223
  const int b    = slot & 3;            // q-row block of 64
  const int half = g / 112;
  const int nt   = g - half * 112;
  const int n  = nt / 7, tp = nt % 7;
  const int tq = (half == 0) ? tp + 1 : tp;
  const int tk = (half == 0) ? tp     : tp + 1;
  const int ntq = n * T_ + tq;
  const int ntk = n * T_ + tk;

  const float* qsrc = q + (size_t)ntq * L_ * (H_ * D_);
  const uint4* kpl = kb + (size_t)ntk * H_ * ENT;
  ushort_t* Ah = (half == 0) ? A1 : A2;

  __shared__ __align__(16) uint4 ks[2][ENT];   // 2 x 28 KB double buffer
  ushort_t* at = (ushort_t*)ks;                // epilogue alias (27.6 KB, in ks[0])

  const int tid  = threadIdx.x;
  const int lane = tid & 63;
  const int wv   = tid >> 6;
  const int quad = lane >> 4;
  const int l15  = lane & 15;
  const int qi_b = 64 * b + 16 * wv;
  // clamped q-row for fp32-direct loads (rows >=196 masked at epilogue)
  const int qrow = (qi_b + l15 > 195) ? 195 : (qi_b + l15);

  float accA[13][4];
  #pragma unroll
  for (int t = 0; t < 13; t++)
    #pragma unroll
    for (int r = 0; r < 4; r++) accA[t][r] = 0.f;

  // per-wave K DMA for head h into buffer bufp (7 vmem ops / wave)
  auto stage = [&](int h, uint4* bufp) {
    #pragma unroll
    for (int r = 0; r < 7; r++)
      GLD_LDS16(kpl + (size_t)h * ENT + 256 * r + 64 * wv + lane,
                (char*)bufp + (256 * r + 64 * wv) * 16);
  };
  // Q fp32 loads for head h (4 vmem ops / lane): lane's q-row = qrow;
  // dc = quad + 4*kk selects the d-octet (same frag map as before).
  auto loadq = [&](int h, float4 (&qv)[2][2]) {
    #pragma unroll
    for (int kk = 0; kk < 2; kk++) {
      const int dc = quad + 4 * kk;
      const float* p = qsrc + (size_t)(1 + qrow) * (H_ * D_) + h * D_ + dc * 8;
      qv[kk][0] = *(const float4*)p;
      qv[kk][1] = *(const float4*)(p + 4);
    }
  };

  // one head: wait(own group landed, keep next head's 11 in flight) ->
  // barrier -> cvt Q regs (scale 1/8, RNE) -> MFMA from bufp -> barrier ->
  // issue head h+2's group into same buffer (parity) -> softmax (pure
  // VALU, overlaps the in-flight DMA).
  auto headbody = [&](int h, uint4* bufp, float4 (&qv)[2][2], bool lastwait) {
    if (lastwait) asm volatile("s_waitcnt vmcnt(0)" ::: "memory");
    else          asm volatile("s_waitcnt vmcnt(11)" ::: "memory");
    __builtin_amdgcn_s_barrier();
    asm volatile("" ::: "memory");       // no LDS read hoists above barrier

    bf16x8 qf[2];
    #pragma unroll
    for (int kk = 0; kk < 2; kk++) {
      uint4 o;
      o.x = pack2(qv[kk][0].x * 0.125f, qv[kk][0].y * 0.125f);
      o.y = pack2(qv[kk][0].z * 0.125f, qv[kk][0].w * 0.125f);
      o.z = pack2(qv[kk][1].x * 0.125f, qv[kk][1].y * 0.125f);
      o.w = pack2(qv[kk][1].z * 0.125f, qv[kk][1].w * 0.125f);
      qf[kk] = *(bf16x8*)&o;
    }

    const ushort_t* bu = (const ushort_t*)bufp;
    floatx4 S[13];
    #pragma unroll
    for (int t = 0; t < 13; t++) S[t] = (floatx4){0.f, 0.f, 0.f, 0.f};
    #pragma unroll
    for (int kk = 0; kk < 2; kk++)
      #pragma unroll
      for (int t = 0; t < 13; t++) {
        bf16x8 bbv = *(const bf16x8*)&bu[((quad + 4 * kk) * KP + 16 * t + l15) * 8];
        S[t] = __builtin_amdgcn_mfma_f32_16x16x32_bf16(qf[kk], bbv, S[t], 0, 0, 0);
      }

    asm volatile("" ::: "memory");       // no LDS read sinks below barrier
    __builtin_amdgcn_s_barrier();        // all waves done reading bufp
    if (h + 2 < H_) {                    // prefetch 2 heads ahead
      loadq(h + 2, qv);
      stage(h + 2, bufp);
      // keep the 11-op issue cluster together; nothing drifts across softmax
      __builtin_amdgcn_sched_barrier(0);
    }

    // softmax over k (196 valid), accumulate P/rowsum (pure VALU, overlaps DMA)
    #pragma unroll
    for (int r = 0; r < 4; r++) {
      float s = 0.f;
      #pragma unroll
      for (int t = 0; t < 13; t++) {
        float e_ = (t == 12 && l15 >= 4) ? 0.f : __expf(S[t][r]);
        S[t][r] = e_;
        s += e_;
      }
      #pragma unroll
      for (int off = 1; off < 16; off <<= 1) s += __shfl_xor(s, off);
      float inv = 1.f / s;
      #pragma unroll
      for (int t = 0; t < 13; t++) accA[t][r] += S[t][r] * inv;
    }
  };

  // prologue: heads 0 and 1 in flight. Issue-order MUST be {Q0,D0} then
  // {Q1,D1} for the vmcnt(11) count to drain exactly head 0 at the first
  // wait — sched_barrier(0) pins the groups.
  float4 qvA[2][2], qvB[2][2];
  loadq(0, qvA); stage(0, ks[0]);
  __builtin_amdgcn_sched_barrier(0);
  loadq(1, qvB); stage(1, ks[1]);
  __builtin_amdgcn_sched_barrier(0);

  #pragma unroll 1
  for (int hh = 0; hh < 6; hh++) {
    headbody(2 * hh,     ks[0], qvA, false);
    headbody(2 * hh + 1, ks[1], qvB, hh == 5);
  }

  // epilogue: transpose accA via LDS (wave-private rows), uint4 stores
  const float s12 = 1.f / 12.f;
  #pragma unroll
  for (int t = 0; t < 13; t++)
    #pragma unroll
    for (int r = 0; r < 4; r++)
      at[(16 * wv + 4 * quad + r) * ATS + 16 * t + l15] = f2bf(accA[t][r] * s12);
  #pragma unroll
  for (int i = 0; i < 7; i++) {
    int e = lane + 64 * i;             // 16 rows x 26 uint4 = 416
    if (e < 416) {
      int row = e / 26, col = e - row * 26;
      uint4 v = *(const uint4*)&at[(16 * wv + row) * ATS + col * 8];
      int qi = qi_b + row;
      if (qi < Q_)
        *(uint4*)(Ah + ((size_t)qi * (N_ * T_) + ntq) * KP + col * 8) = v;
    }
  }
}

// ------------- Stage 2: out[nt,qi,c] = sum_half A_h[qi] @ gather(W_h) ------
// grid (6 c-tiles of 128, 196 qi), block 256. As via DMA (dbuf, skewed
// planes); W gather is wave-private -> ONE barrier per chunk. [round-4
// form: __syncthreads + prefetch-1. The counted-vmcnt/prefetch-2 variant
// REGRESSED (round 5): it de-correlated co-resident blocks' accesses and
// raised HBM traffic 60% — the full drain keeps L2 reuse tight here.]
__global__ __launch_bounds__(256, 4) void mix_kernel(
    const ushort_t* __restrict__ A1, const ushort_t* __restrict__ A2,
    const float* __restrict__ w1, const float* __restrict__ w2,
    const int* __restrict__ idx, float* __restrict__ out) {
  const int ct = blockIdx.x;   // 0..5
  const int qi = blockIdx.y;   // 0..195
  const int tid  = threadIdx.x;
  const int lane = tid & 63;
  const int wv   = tid >> 6;
  const int quad = lane >> 4;
  const int l15  = lane & 15;
  const int p    = lane >> 2;  // k-pair 0..15
  const int cq   = lane & 3;   // c-chunk slot

  __shared__ __align__(16) char As[2][4 * APLANE];   // 2 x 8448 B
  __shared__ ushort_t Ws[128][40];                   // wave-private rows

  // idx regs: this lane's two k-rows per chunk (clamped; A=0 kills pad cols)
  int idxr0[7], idxr1[7];
  #pragma unroll
  for (int kc = 0; kc < 7; kc++) {
    int off = 32 * kc + 2 * p;
    if (off > 194) off = 194;
    int2 pr = *(const int2*)(idx + (size_t)qi * Q_ + off);
    idxr0[kc] = pr.x; idxr1[kc] = pr.y;
  }

  floatx4 acc[8][2];
  #pragma unroll
  for (int mt = 0; mt < 8; mt++)
    #pragma unroll
    for (int u = 0; u < 2; u++) acc[mt][u] = (floatx4){0.f, 0.f, 0.f, 0.f};

  float4 pw[2][2];   // [k-offset j][c-chunk u]
  const int cbase = ct * 128 + wv * 32;

  // ---- preload chunk 0 ----
  {
    const ushort_t* Ah_ = A1;
    #pragma unroll
    for (int r = 0; r < 2; r++)
      GLD_LDS16(Ah_ + ((size_t)qi * 128 + r * 64 + lane) * KP + wv * 8,
                As[0] + wv * APLANE + r * 1024);
    #pragma unroll
    for (int j = 0; j < 2; j++)
      #pragma unroll
      for (int u = 0; u < 2; u++)
        pw[j][u] = *(const float4*)(w1 + (size_t)(j ? idxr1[0] : idxr0[0]) * C_ +
                                    cbase + (cq + 4 * u) * 4);
  }

  #pragma unroll
  for (int ht = 0; ht < 14; ht++) {
    const int half = ht / 7, kc = ht % 7;
    __syncthreads();                 // As[ht&1] DMA + pw gather drained

    // commit this chunk's W (wave-private -> no barrier needed)
    #pragma unroll
    for (int u = 0; u < 2; u++) {
      const float* f0 = (const float*)&pw[0][u];
      const float* f1 = (const float*)&pw[1][u];
      #pragma unroll
      for (int e = 0; e < 4; e++)
        *(unsigned int*)&Ws[wv * 32 + (cq + 4 * u) * 4 + e][2 * p] = pack2(f0[e], f1[e]);
    }

    // issue next chunk's A-DMA + W-gather (in flight through the MFMA phase)
    if (ht + 1 < 14) {
      const int nh = (ht + 1) / 7, nk = (ht + 1) % 7;
      const ushort_t* Ah_ = nh ? A2 : A1;
      const float* w_ = nh ? w2 : w1;
      #pragma unroll
      for (int r = 0; r < 2; r++)
        GLD_LDS16(Ah_ + ((size_t)qi * 128 + r * 64 + lane) * KP + 32 * nk + wv * 8,
                  As[(ht + 1) & 1] + wv * APLANE + r * 1024);
      int r0 = idxr0[nk], r1 = idxr1[nk];
      #pragma unroll
      for (int u = 0; u < 2; u++) {
        pw[0][u] = *(const float4*)(w_ + (size_t)r0 * C_ + cbase + (cq + 4 * u) * 4);
        pw[1][u] = *(const float4*)(w_ + (size_t)r1 * C_ + cbase + (cq + 4 * u) * 4);
      }
    }

    // MFMA phase: LDS only
    const char* ab = As[ht & 1];
    bf16x8 bfv[2];
    #pragma unroll
    for (int u = 0; u < 2; u++)
      bfv[u] = *(const bf16x8*)&Ws[wv * 32 + 16 * u + l15][8 * quad];
    #pragma unroll
    for (int mt = 0; mt < 8; mt++) {
      bf16x8 a = *(const bf16x8*)(ab + quad * APLANE + (16 * mt + l15) * 16);
      acc[mt][0] = __builtin_amdgcn_mfma_f32_16x16x32_bf16(a, bfv[0], acc[mt][0], 0, 0, 0);
      acc[mt][1] = __builtin_amdgcn_mfma_f32_16x16x32_bf16(a, bfv[1], acc[mt][1], 0, 0, 0);
    }
  }

  #pragma unroll
  for (int u = 0; u < 2; u++) {
    const int c = ct * 128 + 32 * wv + 16 * u + l15;
    #pragma unroll
    for (int mt = 0; mt < 8; mt++)
      #pragma unroll
      for (int r = 0; r < 4; r++) {
        int m = 16 * mt + 4 * quad + r;
        out[((size_t)m * L_ + 1 + qi) * C_ + c] = acc[mt][u][r];
      }
  }
  if (qi == 0) {
    #pragma unroll
    for (int u = 0; u < 2; u++) {
      const int c = ct * 128 + 32 * wv + 16 * u + l15;
      #pragma unroll
      for (int mt = 0; mt < 8; mt++)
        #pragma unroll
        for (int r = 0; r < 4; r++) {
          int m = 16 * mt + 4 * quad + r;
          out[(size_t)m * L_ * C_ + c] = 0.f;
        }
    }
  }
}

extern "C" void kernel_launch(void* const* d_in, const int* in_sizes, int n_in,
                              void* d_out, int out_size, void* d_ws, size_t ws_size,
                              hipStream_t stream) {
  const float* q  = (const float*)d_in[0];
  const float* k  = (const float*)d_in[1];
  const float* w1 = (const float*)d_in[2];
  const float* w2 = (const float*)d_in[3];
  const int* idx  = (const int*)d_in[4];
  float* out = (float*)d_out;

  const size_t plane_tot = (size_t)(N_ * T_) * H_ * ENT;   // uint4 entries
  uint4* kb = (uint4*)d_ws;
  ushort_t* A1 = (ushort_t*)(kb + plane_tot);
  size_t Aelems = (size_t)Q_ * (N_ * T_) * KP;
  ushort_t* A2 = A1 + Aelems;

  // zero A buffers: covers k-pad cols and the empty t-slots
  hipMemsetAsync(A1, 0, Aelems * 2 * sizeof(ushort_t), stream);

  convert_kernel<<<dim3(N_ * T_, H_), 256, 0, stream>>>(k, kb);
  attn_kernel<<<dim3(896), 256, 0, stream>>>(q, kb, A1, A2);
  mix_kernel<<<dim3(6, Q_), 256, 0, stream>>>(A1, A2, w1, w2, idx, out);
}